// Round 3
// baseline (152.845 us; speedup 1.0000x reference)
//
#include <hip/hip_runtime.h>
#include <hip/hip_cooperative_groups.h>
#include <math.h>

namespace cg = cooperative_groups;

// Problem constants
#define BB   8
#define NB   81
#define NB1  82
#define HW   76800
#define NTOT (BB * HW)
#define EPS  1e-10f

#define NBLK 512          // total blocks (2 per CU)
#define PERB 64           // chamfer blocks per batch (NBLK/BB)

// Workspace layout (float indices)
#define SB_OFF   0                        // sorted bins [8][81]
#define MAXT_OFF (SB_OFF + BB * NB)       // 648: per-block masked-max partial [512]
#define ST_OFF   (MAXT_OFF + NBLK)        // 1160: stats partials [512][4] sd,sd2,ssq,cnt
#define DA_OFF   (ST_OFF + NBLK * 4)      // 3208: dirA partials [512]
#define A_OFF    (DA_OFF + NBLK)          // 3720: Acand bits [8][83]
#define B_OFF    (A_OFF + BB * 83)        // 4384: Bcand bits [8][83]
#define WS_END   (B_OFF + BB * 83)        // 5048 floats

__device__ __forceinline__ float bsum(float v, float* red) {
    int tid = threadIdx.x;
    red[tid] = v; __syncthreads();
    for (int s = 128; s > 0; s >>= 1) { if (tid < s) red[tid] += red[tid + s]; __syncthreads(); }
    float r = red[0]; __syncthreads();
    return r;
}
__device__ __forceinline__ float bmax(float v, float* red) {
    int tid = threadIdx.x;
    red[tid] = v; __syncthreads();
    for (int s = 128; s > 0; s >>= 1) { if (tid < s) red[tid] = fmaxf(red[tid], red[tid + s]); __syncthreads(); }
    float r = red[0]; __syncthreads();
    return r;
}

__global__ __launch_bounds__(256, 2) void k_all(const float* __restrict__ pred,
                                                const float* __restrict__ tgt,
                                                const float* __restrict__ bins,
                                                const void*  __restrict__ mask,
                                                float* ws, float* out) {
    cg::grid_group grid = cg::this_grid();
    __shared__ float red[256];
    __shared__ float sbin[NB];
    __shared__ float ss[84];            // [-inf, s0..s80, pad, +inf]
    __shared__ int   iA[83], iB[83];
    __shared__ float tmpR[BB][NB1];
    __shared__ float sums8[BB];

    int tid = threadIdx.x, bid = blockIdx.x;

    // ---- mask dtype probe: each wave's 64 lanes inspect the first 64 words ----
    unsigned pv = ((const unsigned*)mask)[tid & 63];
    bool alli = __all(pv == 0u || pv == 1u);
    bool allf = __all(pv == 0u || pv == 0x3F800000u);
    int mode = alli ? 1 : (allf ? 2 : 0);   // 1=int32, 2=float, 0=byte

    // ================= Phase 0 =================
    // bins rank-sort (blocks 0..7), A/B sentinel init (block 8)
    if (bid < BB) {
        if (tid < NB) sbin[tid] = bins[bid * NB + tid];
        __syncthreads();
        if (tid < NB) {
            float v = sbin[tid];
            int r = 0;
            for (int k = 0; k < NB; ++k) {
                float u = sbin[k];
                r += (u < v) || (u == v && k < tid);   // stable, exact permutation
            }
            ws[SB_OFF + bid * NB + r] = v;
        }
    }
    if (bid == 8) {
        int* wi = (int*)ws;
        for (int i = tid; i < BB * 83; i += 256) {
            wi[A_OFF + i] = 0xFF800000;   // -inf bits
            wi[B_OFF + i] = 0x7F800000;   // +inf bits
        }
    }

    // stats (silog/l2 sums, mask count) + masked max(target), float4 pass
    float sd = 0.f, sd2 = 0.f, ssq = 0.f, cnt = 0.f, mt = 0.f;
    const int n4 = NTOT / 4;
    for (int i = bid * 256 + tid; i < n4; i += NBLK * 256) {
        float4 p4 = ((const float4*)pred)[i];
        float4 t4 = ((const float4*)tgt)[i];
        int m0, m1, m2, m3;
        if (mode == 0) {
            unsigned um = ((const unsigned*)mask)[i];
            m0 = um & 0xFF; m1 = (um >> 8) & 0xFF; m2 = (um >> 16) & 0xFF; m3 = (um >> 24) & 0xFF;
        } else if (mode == 1) {
            uint4 u4 = ((const uint4*)mask)[i];
            m0 = u4.x; m1 = u4.y; m2 = u4.z; m3 = u4.w;
        } else {
            float4 f4 = ((const float4*)mask)[i];
            m0 = f4.x != 0.f; m1 = f4.y != 0.f; m2 = f4.z != 0.f; m3 = f4.w != 0.f;
        }
        if (m0) { float d = logf((p4.x + EPS) / (t4.x + EPS)); sd += d; sd2 += d*d; float e = p4.x - t4.x; ssq += e*e; cnt += 1.f; mt = fmaxf(mt, t4.x); }
        if (m1) { float d = logf((p4.y + EPS) / (t4.y + EPS)); sd += d; sd2 += d*d; float e = p4.y - t4.y; ssq += e*e; cnt += 1.f; mt = fmaxf(mt, t4.y); }
        if (m2) { float d = logf((p4.z + EPS) / (t4.z + EPS)); sd += d; sd2 += d*d; float e = p4.z - t4.z; ssq += e*e; cnt += 1.f; mt = fmaxf(mt, t4.z); }
        if (m3) { float d = logf((p4.w + EPS) / (t4.w + EPS)); sd += d; sd2 += d*d; float e = p4.w - t4.w; ssq += e*e; cnt += 1.f; mt = fmaxf(mt, t4.w); }
    }
    {
        float r0 = bsum(sd, red);
        float r1 = bsum(sd2, red);
        float r2 = bsum(ssq, red);
        float r3 = bsum(cnt, red);
        float rm = bmax(mt, red);
        if (tid == 0) {
            float* p4 = &ws[ST_OFF + bid * 4];
            p4[0] = r0; p4[1] = r1; p4[2] = r2; p4[3] = r3;
            ws[MAXT_OFF + bid] = rm;
        }
    }

    grid.sync();

    // ================= Phase 1: chamfer =================
    float mp = -INFINITY;
    for (int i = tid; i < NBLK; i += 256) mp = fmaxf(mp, ws[MAXT_OFF + i]);
    float maxT = bmax(mp, red);
    float maxB = bmax(tid < BB ? ws[SB_OFF + tid * NB + (NB - 1)] : -INFINITY, red);
    float mx = fmaxf(maxT, maxB), mn = fminf(maxT, maxB);
    float pad = mx + (mx - mn) + 1.0f;

    int b = bid >> 6, c = bid & 63;
    if (tid < NB) ss[1 + tid] = ws[SB_OFF + b * NB + tid];
    if (tid == 0) { ss[0] = -INFINITY; ss[NB1] = pad; ss[NB1 + 1] = INFINITY; }
    if (tid < 83) { iA[tid] = 0xFF800000; iB[tid] = 0x7F800000; }
    __syncthreads();

    float dA = 0.f;
    const int hw4 = HW / 4;
    const float4* tb4 = (const float4*)(tgt + b * HW);
    for (int i = c * 256 + tid; i < hw4; i += PERB * 256) {
        float4 t4 = tb4[i];
        int m0, m1, m2, m3;
        if (mode == 0) {
            unsigned um = ((const unsigned*)mask)[b * hw4 + i];
            m0 = um & 0xFF; m1 = (um >> 8) & 0xFF; m2 = (um >> 16) & 0xFF; m3 = (um >> 24) & 0xFF;
        } else if (mode == 1) {
            uint4 u4 = ((const uint4*)mask)[b * hw4 + i];
            m0 = u4.x; m1 = u4.y; m2 = u4.z; m3 = u4.w;
        } else {
            float4 f4 = ((const float4*)mask)[b * hw4 + i];
            m0 = f4.x != 0.f; m1 = f4.y != 0.f; m2 = f4.z != 0.f; m3 = f4.w != 0.f;
        }
        float v0 = m0 ? t4.x : pad;
        float v1 = m1 ? t4.y : pad;
        float v2 = m2 ? t4.z : pad;
        float v3 = m3 ? t4.w : pad;

        int c0 = 0, c1 = 0, c2 = 0, c3 = 0;
#pragma unroll
        for (int k = 1; k <= NB1; ++k) {
            float s = ss[k];
            c0 += (s <= v0); c1 += (s <= v1); c2 += (s <= v2); c3 += (s <= v3);
        }
        {
            float lo = ss[c0], hi = ss[c0 + 1];
            float dl = v0 - lo, dh = hi - v0;
            dA += fminf(dl * dl, dh * dh);
            int bits = __float_as_int(v0);
            atomicMax(&iA[c0], bits); atomicMin(&iB[c0], bits);
        }
        {
            float lo = ss[c1], hi = ss[c1 + 1];
            float dl = v1 - lo, dh = hi - v1;
            dA += fminf(dl * dl, dh * dh);
            int bits = __float_as_int(v1);
            atomicMax(&iA[c1], bits); atomicMin(&iB[c1], bits);
        }
        {
            float lo = ss[c2], hi = ss[c2 + 1];
            float dl = v2 - lo, dh = hi - v2;
            dA += fminf(dl * dl, dh * dh);
            int bits = __float_as_int(v2);
            atomicMax(&iA[c2], bits); atomicMin(&iB[c2], bits);
        }
        {
            float lo = ss[c3], hi = ss[c3 + 1];
            float dl = v3 - lo, dh = hi - v3;
            dA += fminf(dl * dl, dh * dh);
            int bits = __float_as_int(v3);
            atomicMax(&iA[c3], bits); atomicMin(&iB[c3], bits);
        }
    }

    float rA = bsum(dA, red);               // includes __syncthreads -> iA/iB settled
    if (tid == 0) ws[DA_OFF + bid] = rA;
    if (tid < 83) {
        atomicMax((int*)ws + A_OFF + b * 83 + tid, iA[tid]);
        atomicMin((int*)ws + B_OFF + b * 83 + tid, iB[tid]);
    }

    grid.sync();

    // ================= Phase 2: finalize (block 0) =================
    if (bid == 0) {
        float s0 = 0.f, s1 = 0.f, s2 = 0.f, s3 = 0.f, sa = 0.f;
        for (int i = tid; i < NBLK; i += 256) {
            const float* p4 = &ws[ST_OFF + i * 4];
            s0 += p4[0]; s1 += p4[1]; s2 += p4[2]; s3 += p4[3];
            sa += ws[DA_OFF + i];
        }
        s0 = bsum(s0, red); s1 = bsum(s1, red); s2 = bsum(s2, red);
        s3 = bsum(s3, red); sa = bsum(sa, red);

        if (tid < BB) {
            const int* Ac = (const int*)ws + A_OFF + tid * 83;
            const int* Bc = (const int*)ws + B_OFF + tid * 83;
            float rmin = INFINITY;
            for (int k = NB1 - 1; k >= 0; --k) {
                rmin = fminf(rmin, __int_as_float(Bc[k + 1]));
                float sk = (k < NB) ? ws[SB_OFF + tid * NB + k] : pad;
                float d = rmin - sk;
                tmpR[tid][k] = d * d;
            }
            float lmax = -INFINITY, sb = 0.f;
            for (int k = 0; k < NB1; ++k) {
                lmax = fmaxf(lmax, __int_as_float(Ac[k]));
                float sk = (k < NB) ? ws[SB_OFF + tid * NB + k] : pad;
                float d = sk - lmax;
                sb += fminf(d * d, tmpR[tid][k]);
            }
            sums8[tid] = sb;
        }
        __syncthreads();
        if (tid == 0) {
            float sumB = 0.f;
            for (int i = 0; i < BB; ++i) sumB += sums8[i];
            float m1 = s0 / s3, m2 = s1 / s3;
            float silog = 10.0f * sqrtf(fmaxf(m2 - 0.85f * m1 * m1, 0.0f));
            float l2 = sqrtf(s2 / s3);
            float chamfer = (sa + sumB) / (float)BB;
            out[0] = l2 + silog + chamfer;
        }
    }
}

extern "C" void kernel_launch(void* const* d_in, const int* in_sizes, int n_in,
                              void* d_out, int out_size, void* d_ws, size_t ws_size,
                              hipStream_t stream) {
    const float* pred = (const float*)d_in[0];
    const float* tgt  = (const float*)d_in[1];
    const float* bins = (const float*)d_in[2];
    const void*  mask = d_in[3];
    float* ws  = (float*)d_ws;
    float* out = (float*)d_out;

    void* args[] = { (void*)&pred, (void*)&tgt, (void*)&bins, (void*)&mask,
                     (void*)&ws, (void*)&out };
    hipLaunchCooperativeKernel((void*)k_all, dim3(NBLK), dim3(256), args, 0, stream);
}

// Round 4
// 65.300 us; speedup vs baseline: 2.3407x; 2.3407x over previous
//
#include <hip/hip_runtime.h>
#include <math.h>

// Problem constants
#define BB   8
#define NB   81            // real bins per batch
#define HW   76800
#define HW4  19200         // HW/4
#define EPS  1e-10f

#define NBLK 512           // blocks for both passes
#define PERB 64            // chunks per batch (NBLK/BB)
#define CSTR (PERB * 256)  // float4 stride within a batch

// ws float-index layout (all plain-store initialized every call -> garbage-immune)
#define SB_OFF 0                      // sorted bins [8][81]            -> 648
#define ST_OFF 648                    // K1 partials [512][5] sd,sd2,ssq,cnt,maxT -> 3208
#define DA_OFF 3208                   // K2 dirA partials [512]         -> 3720
#define CA_OFF 3720                   // A candidates (max) bits [8][83] -> 4384
#define CB_OFF 4384                   // B candidates (min) bits [8][83] -> 5048
#define TK_OFF 5048                   // ticket counter (uint), K1 zeroes it

__device__ __forceinline__ int probe_mode(const void* mask, int tid) {
    // every wave inspects the same first 64 words -> uniform result
    unsigned pv = ((const unsigned*)mask)[tid & 63];
    bool alli = __all(pv == 0u || pv == 1u);            // int32 0/1
    bool allf = __all(pv == 0u || pv == 0x3F800000u);   // float 0/1
    return alli ? 1 : (allf ? 2 : 0);                   // 0 = byte
}

__device__ __forceinline__ void mask4(const void* mask, int mode, int widx,
                                      int& m0, int& m1, int& m2, int& m3) {
    if (mode == 1)      { uint4  u = ((const uint4*) mask)[widx]; m0 = u.x; m1 = u.y; m2 = u.z; m3 = u.w; }
    else if (mode == 2) { float4 f = ((const float4*)mask)[widx]; m0 = f.x != 0.f; m1 = f.y != 0.f; m2 = f.z != 0.f; m3 = f.w != 0.f; }
    else { unsigned um = ((const unsigned*)mask)[widx];
           m0 = um & 0xFF; m1 = (um >> 8) & 0xFF; m2 = (um >> 16) & 0xFF; m3 = (um >> 24) & 0xFF; }
}

__device__ __forceinline__ float bsum(float v, float* red) {
    int tid = threadIdx.x;
    red[tid] = v; __syncthreads();
    for (int s = 128; s > 0; s >>= 1) { if (tid < s) red[tid] += red[tid + s]; __syncthreads(); }
    float r = red[0]; __syncthreads();
    return r;
}
__device__ __forceinline__ float bmax(float v, float* red) {
    int tid = threadIdx.x;
    red[tid] = v; __syncthreads();
    for (int s = 128; s > 0; s >>= 1) { if (tid < s) red[tid] = fmaxf(red[tid], red[tid + s]); __syncthreads(); }
    float r = red[0]; __syncthreads();
    return r;
}

// ---------------------------------------------------------------------------
// Pass 1: silog/l2 stats + masked-max partials (pad-independent), bin sort,
// candidate sentinels + ticket init. All stores plain -> safe vs any ws state.
__global__ __launch_bounds__(256, 2) void k_pass1(const float* __restrict__ pred,
                                                  const float* __restrict__ tgt,
                                                  const float* __restrict__ bins,
                                                  const void*  __restrict__ mask,
                                                  float* __restrict__ ws) {
    __shared__ float red[256];
    __shared__ float sbin[NB];
    int tid = threadIdx.x, bid = blockIdx.x;
    int b = bid >> 6, c = bid & 63;
    int mode = probe_mode(mask, tid);

    if (bid < BB) {                       // rank-sort this batch's 81 bins
        if (tid < NB) sbin[tid] = bins[bid * NB + tid];
        __syncthreads();
        if (tid < NB) {
            float v = sbin[tid]; int r = 0;
            for (int k = 0; k < NB; ++k) { float u = sbin[k]; r += (u < v) || (u == v && k < tid); }
            ws[SB_OFF + bid * NB + r] = v;
        }
    }
    if (bid == 8) {                       // sentinels + ticket (plain stores)
        int* wi = (int*)ws;
        for (int i = tid; i < BB * 83; i += 256) {
            wi[CA_OFF + i] = 0xFF800000;  // -inf bits (int order == float order for positives)
            wi[CB_OFF + i] = 0x7F800000;  // +inf bits
        }
        if (tid == 0) ((unsigned*)ws)[TK_OFF] = 0u;
    }

    // stats + masked max, per-batch chunk mapping (matches pass 2 for L2 reuse)
    const float4* p4p = (const float4*)(pred + (size_t)b * HW);
    const float4* t4p = (const float4*)(tgt  + (size_t)b * HW);
    float sd = 0.f, sd2 = 0.f, ssq = 0.f, cnt = 0.f, mt = 0.f;
    for (int i = c * 256 + tid; i < HW4; i += CSTR) {
        float4 p = p4p[i], t = t4p[i];
        int m0, m1, m2, m3;
        mask4(mask, mode, b * HW4 + i, m0, m1, m2, m3);
        if (m0) { float d = __logf((p.x + EPS) / (t.x + EPS)); sd += d; sd2 += d*d; float e = p.x - t.x; ssq += e*e; cnt += 1.f; mt = fmaxf(mt, t.x); }
        if (m1) { float d = __logf((p.y + EPS) / (t.y + EPS)); sd += d; sd2 += d*d; float e = p.y - t.y; ssq += e*e; cnt += 1.f; mt = fmaxf(mt, t.y); }
        if (m2) { float d = __logf((p.z + EPS) / (t.z + EPS)); sd += d; sd2 += d*d; float e = p.z - t.z; ssq += e*e; cnt += 1.f; mt = fmaxf(mt, t.z); }
        if (m3) { float d = __logf((p.w + EPS) / (t.w + EPS)); sd += d; sd2 += d*d; float e = p.w - t.w; ssq += e*e; cnt += 1.f; mt = fmaxf(mt, t.w); }
    }
    float r0 = bsum(sd, red);
    float r1 = bsum(sd2, red);
    float r2 = bsum(ssq, red);
    float r3 = bsum(cnt, red);
    float rm = bmax(mt, red);
    if (tid == 0) {
        float* p5 = &ws[ST_OFF + bid * 5];
        p5[0] = r0; p5[1] = r1; p5[2] = r2; p5[3] = r3; p5[4] = rm;
    }
}

// ---------------------------------------------------------------------------
// Pass 2: chamfer with pad known. Invalid pixels skipped entirely (their dirA
// term is exactly 0; their dirB effect is the analytic pad candidate).
// Last block (ticket) folds everything in fixed order and writes the output.
__global__ __launch_bounds__(256, 2) void k_pass2(const float* __restrict__ tgt,
                                                  const void*  __restrict__ mask,
                                                  float* __restrict__ ws,
                                                  float* __restrict__ out) {
    __shared__ float red[256];
    __shared__ float ss[84];           // [-inf, s0..s80, pad, +inf]
    __shared__ int   iA[83], iB[83];
    __shared__ float tmpR[BB][NB + 1];
    __shared__ float sums8[BB];
    __shared__ unsigned s_tick;

    int tid = threadIdx.x, bid = blockIdx.x;
    int b = bid >> 6, c = bid & 63;
    int mode = probe_mode(mask, tid);

    // pad from pass-1 partials (each block redundantly; ~520 L2-hot loads)
    float mp = -INFINITY;
    for (int i = tid; i < NBLK; i += 256) mp = fmaxf(mp, ws[ST_OFF + i * 5 + 4]);
    float maxT = bmax(mp, red);
    float maxB = bmax(tid < BB ? ws[SB_OFF + tid * NB + (NB - 1)] : -INFINITY, red);
    float mx = fmaxf(maxT, maxB), mn = fminf(maxT, maxB);
    float pad = mx + (mx - mn) + 1.0f;

    if (tid < NB) ss[1 + tid] = ws[SB_OFF + b * NB + tid];
    if (tid == 0) { ss[0] = -INFINITY; ss[NB + 1] = pad; ss[NB + 2] = INFINITY; }
    if (tid < 83) { iA[tid] = 0xFF800000; iB[tid] = 0x7F800000; }
    __syncthreads();

    float dA = 0.f;
    const float4* t4p = (const float4*)(tgt + (size_t)b * HW);
    for (int i = c * 256 + tid; i < HW4; i += CSTR) {
        float4 t = t4p[i];
        int m0, m1, m2, m3;
        mask4(mask, mode, b * HW4 + i, m0, m1, m2, m3);
        float v0 = m0 ? t.x : -1.f;    // -1 < all bins -> slot 0, discarded by guard
        float v1 = m1 ? t.y : -1.f;
        float v2 = m2 ? t.z : -1.f;
        float v3 = m3 ? t.w : -1.f;

        int c0 = 0, c1 = 0, c2 = 0, c3 = 0;
#pragma unroll
        for (int k = 1; k <= NB; ++k) {            // valid t < pad always -> 81 compares suffice
            float s = ss[k];
            c0 += (s <= v0); c1 += (s <= v1); c2 += (s <= v2); c3 += (s <= v3);
        }
        if (m0) { float lo = ss[c0], hi = ss[c0 + 1]; float dl = v0 - lo, dh = hi - v0;
                  dA += fminf(dl * dl, dh * dh); int bt = __float_as_int(v0);
                  atomicMax(&iA[c0], bt); atomicMin(&iB[c0], bt); }
        if (m1) { float lo = ss[c1], hi = ss[c1 + 1]; float dl = v1 - lo, dh = hi - v1;
                  dA += fminf(dl * dl, dh * dh); int bt = __float_as_int(v1);
                  atomicMax(&iA[c1], bt); atomicMin(&iB[c1], bt); }
        if (m2) { float lo = ss[c2], hi = ss[c2 + 1]; float dl = v2 - lo, dh = hi - v2;
                  dA += fminf(dl * dl, dh * dh); int bt = __float_as_int(v2);
                  atomicMax(&iA[c2], bt); atomicMin(&iB[c2], bt); }
        if (m3) { float lo = ss[c3], hi = ss[c3 + 1]; float dl = v3 - lo, dh = hi - v3;
                  dA += fminf(dl * dl, dh * dh); int bt = __float_as_int(v3);
                  atomicMax(&iA[c3], bt); atomicMin(&iB[c3], bt); }
    }

    float rA = bsum(dA, red);                      // syncthreads inside -> iA/iB settled
    if (tid == 0) ws[DA_OFF + bid] = rA;
    if (tid < 83) {
        atomicMax((int*)ws + CA_OFF + b * 83 + tid, iA[tid]);
        atomicMin((int*)ws + CB_OFF + b * 83 + tid, iB[tid]);
    }

    // -------- last-block finalize via ticket (K1 zeroed the counter) --------
    __threadfence();
    if (tid == 0) s_tick = atomicAdd((unsigned*)ws + TK_OFF, 1u);
    __syncthreads();
    if (s_tick != NBLK - 1) return;
    __threadfence();

    float s0 = 0.f, s1 = 0.f, s2 = 0.f, s3 = 0.f, sa = 0.f;
    for (int i = tid; i < NBLK; i += 256) {
        const float* p5 = &ws[ST_OFF + i * 5];
        s0 += p5[0]; s1 += p5[1]; s2 += p5[2]; s3 += p5[3];
        sa += ws[DA_OFF + i];
    }
    s0 = bsum(s0, red); s1 = bsum(s1, red); s2 = bsum(s2, red);
    s3 = bsum(s3, red); sa = bsum(sa, red);

    if (tid < BB) {
        const int*   Ac  = (const int*)ws + CA_OFF + tid * 83;
        const int*   Bc  = (const int*)ws + CB_OFF + tid * 83;
        const float* SBb = ws + SB_OFF + tid * NB;
        float cb = 0.f;                                  // this batch's valid count
        for (int j = 0; j < PERB; ++j) cb += ws[ST_OFF + (tid * PERB + j) * 5 + 3];
        bool anyInv = (cb != (float)HW);

        // backward: R[k] = min target in slots > k (pad targets enter via rmin init)
        float rmin = anyInv ? pad : INFINITY;
        for (int k = NB; k >= 0; --k) {                  // k=81 is the pad bin
            rmin = fminf(rmin, __int_as_float(Bc[k + 1]));
            float sk = (k < NB) ? SBb[k] : pad;
            float d = rmin - sk;
            tmpR[tid][k] = d * d;
        }
        // forward: L[k] = max target in slots <= k; combine
        float lmax = -INFINITY, sb = 0.f;
        for (int k = 0; k <= NB; ++k) {
            lmax = fmaxf(lmax, __int_as_float(Ac[k]));
            float sk = (k < NB) ? SBb[k] : pad;
            float d = sk - lmax;
            sb += fminf(d * d, tmpR[tid][k]);
        }
        sums8[tid] = sb;
    }
    __syncthreads();
    if (tid == 0) {
        float sumB = 0.f;
        for (int i = 0; i < BB; ++i) sumB += sums8[i];
        float m1 = s0 / s3, m2 = s1 / s3;
        float silog = 10.0f * sqrtf(fmaxf(m2 - 0.85f * m1 * m1, 0.0f));
        float l2 = sqrtf(s2 / s3);
        float chamfer = (sa + sumB) / (float)BB;
        out[0] = l2 + silog + chamfer;
    }
}

// ---------------------------------------------------------------------------
extern "C" void kernel_launch(void* const* d_in, const int* in_sizes, int n_in,
                              void* d_out, int out_size, void* d_ws, size_t ws_size,
                              hipStream_t stream) {
    (void)in_sizes; (void)n_in; (void)out_size; (void)ws_size;
    const float* pred = (const float*)d_in[0];
    const float* tgt  = (const float*)d_in[1];
    const float* bins = (const float*)d_in[2];
    const void*  mask = d_in[3];
    float* ws  = (float*)d_ws;
    float* out = (float*)d_out;

    k_pass1<<<NBLK, 256, 0, stream>>>(pred, tgt, bins, mask, ws);
    k_pass2<<<NBLK, 256, 0, stream>>>(tgt, mask, ws, out);
}

// Round 5
// 36.167 us; speedup vs baseline: 4.2261x; 1.8055x over previous
//
#include <hip/hip_runtime.h>
#include <math.h>

// Problem constants
#define BB   8
#define NB   81
#define HW   76800
#define HW4  19200
#define EPS  1e-10f

#define K1B  512           // K1 blocks (64 per batch)
#define K2B  64            // K2 blocks (8 per batch)
#define K2T  1024
#define LUTN 512

// ws float-index layout (ST/CA/CB/TK re-initialized by K1 every call)
#define ST_OFF 0                 // [512][5]: sd, sd2, ssq, cnt, maxT   (plain stores)
#define CA_OFF 2560              // [8][82] int bits: per-slot MAX valid target
#define CB_OFF 3216              // [8][82] int bits: per-slot MIN valid target
#define DA_OFF 3872              // [64] dirA block sums (atomicExch)
#define TK_OFF 3936              // ticket counter (unsigned)

__device__ __forceinline__ int probe_mode(const void* mask, int tid) {
    unsigned pv = ((const unsigned*)mask)[tid & 63];
    bool alli = __all(pv == 0u || pv == 1u);
    bool allf = __all(pv == 0u || pv == 0x3F800000u);
    return alli ? 1 : (allf ? 2 : 0);      // 1=int32, 2=float, 0=byte
}

__device__ __forceinline__ void mask4(const void* mask, int mode, int widx,
                                      int& m0, int& m1, int& m2, int& m3) {
    if (mode == 1)      { uint4  u = ((const uint4*) mask)[widx]; m0 = u.x; m1 = u.y; m2 = u.z; m3 = u.w; }
    else if (mode == 2) { float4 f = ((const float4*)mask)[widx]; m0 = f.x != 0.f; m1 = f.y != 0.f; m2 = f.z != 0.f; m3 = f.w != 0.f; }
    else { unsigned um = ((const unsigned*)mask)[widx];
           m0 = um & 0xFF; m1 = (um >> 8) & 0xFF; m2 = (um >> 16) & 0xFF; m3 = (um >> 24) & 0xFF; }
}

// ---------------------------------------------------------------------------
// K1: silog/l2 stats + masked-max partials (all pad-independent), plus
// sentinel/ticket re-init. Plain stores only; K2 sees them via the dispatch
// boundary. 256 threads/block.
__global__ __launch_bounds__(256, 2) void k_stats(const float* __restrict__ pred,
                                                  const float* __restrict__ tgt,
                                                  const void*  __restrict__ mask,
                                                  float* __restrict__ ws) {
    __shared__ float red[256];
    int tid = threadIdx.x, bid = blockIdx.x;
    int b = bid >> 6, c = bid & 63;
    int mode = probe_mode(mask, tid);

    if (bid == 8) {                        // re-init sentinels + ticket each call
        int* wi = (int*)ws;
        for (int i = tid; i < BB * 82; i += 256) {
            wi[CA_OFF + i] = 0xFF800000;   // -inf bits
            wi[CB_OFF + i] = 0x7F800000;   // +inf bits
        }
        if (tid == 0) ((unsigned*)ws)[TK_OFF] = 0u;
    }

    const float4* p4p = (const float4*)(pred + (size_t)b * HW);
    const float4* t4p = (const float4*)(tgt  + (size_t)b * HW);
    float sd = 0.f, sd2 = 0.f, ssq = 0.f, cnt = 0.f, mt = 0.f;
    for (int i = c * 256 + tid; i < HW4; i += 64 * 256) {
        float4 p = p4p[i], t = t4p[i];
        int m0, m1, m2, m3;
        mask4(mask, mode, b * HW4 + i, m0, m1, m2, m3);
        if (m0) { float d = __logf((p.x + EPS) / (t.x + EPS)); sd += d; sd2 += d*d; float e = p.x - t.x; ssq += e*e; cnt += 1.f; mt = fmaxf(mt, t.x); }
        if (m1) { float d = __logf((p.y + EPS) / (t.y + EPS)); sd += d; sd2 += d*d; float e = p.y - t.y; ssq += e*e; cnt += 1.f; mt = fmaxf(mt, t.y); }
        if (m2) { float d = __logf((p.z + EPS) / (t.z + EPS)); sd += d; sd2 += d*d; float e = p.z - t.z; ssq += e*e; cnt += 1.f; mt = fmaxf(mt, t.z); }
        if (m3) { float d = __logf((p.w + EPS) / (t.w + EPS)); sd += d; sd2 += d*d; float e = p.w - t.w; ssq += e*e; cnt += 1.f; mt = fmaxf(mt, t.w); }
    }
    // fixed-tree reductions (deterministic)
    int t_ = tid;
    red[t_] = sd;  __syncthreads(); for (int s = 128; s > 0; s >>= 1) { if (t_ < s) red[t_] += red[t_ + s]; __syncthreads(); } float r0 = red[0]; __syncthreads();
    red[t_] = sd2; __syncthreads(); for (int s = 128; s > 0; s >>= 1) { if (t_ < s) red[t_] += red[t_ + s]; __syncthreads(); } float r1 = red[0]; __syncthreads();
    red[t_] = ssq; __syncthreads(); for (int s = 128; s > 0; s >>= 1) { if (t_ < s) red[t_] += red[t_ + s]; __syncthreads(); } float r2 = red[0]; __syncthreads();
    red[t_] = cnt; __syncthreads(); for (int s = 128; s > 0; s >>= 1) { if (t_ < s) red[t_] += red[t_ + s]; __syncthreads(); } float r3 = red[0]; __syncthreads();
    red[t_] = mt;  __syncthreads(); for (int s = 128; s > 0; s >>= 1) { if (t_ < s) red[t_] = fmaxf(red[t_], red[t_ + s]); __syncthreads(); } float r4 = red[0];
    if (tid == 0) {
        float* p5 = &ws[ST_OFF + bid * 5];
        p5[0] = r0; p5[1] = r1; p5[2] = r2; p5[3] = r3; p5[4] = r4;
    }
}

// ---------------------------------------------------------------------------
// K2: chamfer (pad known from K1 partials). 64 blocks x 1024 threads.
// Cross-block data flows ONLY through device-scope atomics (no fences).
// Winner block (ticket) folds everything in fixed order and writes out.
__device__ __forceinline__ float bsum1024(float v, float* red) {
    int t = threadIdx.x;
    red[t] = v; __syncthreads();
    for (int s = 512; s > 0; s >>= 1) { if (t < s) red[t] += red[t + s]; __syncthreads(); }
    float r = red[0]; __syncthreads();
    return r;
}
__device__ __forceinline__ float bmax1024(float v, float* red) {
    int t = threadIdx.x;
    red[t] = v; __syncthreads();
    for (int s = 512; s > 0; s >>= 1) { if (t < s) red[t] = fmaxf(red[t], red[t + s]); __syncthreads(); }
    float r = red[0]; __syncthreads();
    return r;
}

__global__ __launch_bounds__(1024, 1) void k_chamfer(const float* __restrict__ tgt,
                                                     const float* __restrict__ bins,
                                                     const void*  __restrict__ mask,
                                                     float* __restrict__ ws,
                                                     float* __restrict__ out) {
    __shared__ float red[1024];
    __shared__ float sraw[NB], ssrt[NB];
    __shared__ int   lut[LUTN];
    __shared__ int   iA[82], iB[82];
    __shared__ unsigned s_tick;
    // winner-phase scratch
    __shared__ float allb[BB * NB], sbAll[BB * NB];
    __shared__ float fA[BB * 82], fB[BB * 82];
    __shared__ float tmpR[BB][82];
    __shared__ float out8[BB];

    int tid = threadIdx.x, bid = blockIdx.x;
    int b = bid >> 3, c = bid & 7;
    int mode = probe_mode(mask, tid);

    // pad = f(global maxT, global maxB)
    float mp = (tid < K1B) ? ws[ST_OFF + tid * 5 + 4] : -INFINITY;
    float maxT = bmax1024(mp, red);
    float mb = (tid < BB * NB) ? bins[tid] : -INFINITY;
    float maxB = bmax1024(mb, red);
    float mx = fmaxf(maxT, maxB), mn = fminf(maxT, maxB);
    float pad = mx + (mx - mn) + 1.0f;

    // sort own batch's bins (rank sort)
    if (tid < NB) sraw[tid] = bins[b * NB + tid];
    __syncthreads();
    if (tid < NB) {
        float v = sraw[tid]; int r = 0;
        for (int k = 0; k < NB; ++k) { float u = sraw[k]; r += (u < v) || (u == v && k < tid); }
        ssrt[r] = v;
    }
    if (tid < 82) { iA[tid] = 0xFF800000; iB[tid] = 0x7F800000; }
    __syncthreads();

    // LUT: lut[q] = #bins < left_edge(q)
    float lo = ssrt[0], hi = ssrt[NB - 1];
    float w = (hi - lo) / (float)LUTN;
    float scale = (hi > lo) ? (float)LUTN / (hi - lo) : 0.f;
    if (tid < LUTN) {
        float edge = lo + (float)tid * w;
        int l = 0, r = NB;
        while (l < r) { int m = (l + r) >> 1; if (ssrt[m] < edge) l = m + 1; else r = m; }
        lut[tid] = l;
    }
    __syncthreads();

    // main chamfer loop (valid pixels only)
    float dA = 0.f;
    const float4* t4p = (const float4*)(tgt + (size_t)b * HW);
    for (int i = c * K2T + tid; i < HW4; i += 8 * K2T) {
        float4 t = t4p[i];
        int m0, m1, m2, m3;
        mask4(mask, mode, b * HW4 + i, m0, m1, m2, m3);
        float tv[4] = { t.x, t.y, t.z, t.w };
        int   mv[4] = { m0, m1, m2, m3 };
#pragma unroll
        for (int e = 0; e < 4; ++e) {
            if (!mv[e]) continue;
            float v = tv[e];
            int q = (int)((v - lo) * scale);
            q = q < 0 ? 0 : (q > LUTN - 1 ? LUTN - 1 : q);
            int s = lut[q];
            while (s < NB && ssrt[s] <= v) ++s;
            while (s > 0 && ssrt[s - 1] > v) --s;
            float lof = (s > 0)  ? ssrt[s - 1] : -INFINITY;
            float hif = (s < NB) ? ssrt[s]     : pad;       // pad is the upper flank
            float dl = v - lof, dh = hif - v;
            dA += fminf(dl * dl, dh * dh);
            int bits = __float_as_int(v);
            atomicMax(&iA[s], bits);
            atomicMin(&iB[s], bits);
        }
    }

    float rA = bsum1024(dA, red);           // syncs inside -> iA/iB settled
    // global merge: device-scope atomics only (coherent point, no fences)
    if (tid < 82) {
        atomicMax((int*)ws + CA_OFF + b * 82 + tid, iA[tid]);
        atomicMin((int*)ws + CB_OFF + b * 82 + tid, iB[tid]);
    }
    if (tid == 0) atomicExch(&ws[DA_OFF + bid], rA);
    // each wave drains ITS OWN vmem (atomics) before the barrier -> all of this
    // block's RMWs have completed at the coherent point before the ticket bump
    asm volatile("s_waitcnt vmcnt(0)" ::: "memory");
    __syncthreads();
    if (tid == 0) s_tick = atomicAdd((unsigned*)ws + TK_OFF, 1u);
    __syncthreads();
    if (s_tick != K2B - 1) return;

    // ---------------- winner block: fold + sweep + output ----------------
    // re-sort ALL batches' bins locally (no cross-block sorted-bin traffic)
    if (tid < BB * NB) allb[tid] = bins[tid];
    __syncthreads();
    if (tid < BB * NB) {
        int b2 = tid / NB, j = tid - b2 * NB;
        float v = allb[tid]; int r = 0;
        for (int k = 0; k < NB; ++k) { float u = allb[b2 * NB + k]; r += (u < v) || (u == v && k < j); }
        sbAll[b2 * NB + r] = v;
    }
    // candidates via agent-scope atomic loads (coherent point)
    if (tid < BB * 82) {
        int va = __hip_atomic_load((int*)ws + CA_OFF + tid, __ATOMIC_RELAXED, __HIP_MEMORY_SCOPE_AGENT);
        int vb = __hip_atomic_load((int*)ws + CB_OFF + tid, __ATOMIC_RELAXED, __HIP_MEMORY_SCOPE_AGENT);
        fA[tid] = __int_as_float(va);
        fB[tid] = __int_as_float(vb);
    }
    __syncthreads();

    // per-batch direction-B sweep (8 threads)
    if (tid < BB) {
        const float* SBb = &sbAll[tid * NB];
        float cntb = 0.f;
        for (int j = 0; j < 64; ++j) cntb += ws[ST_OFF + (tid * 64 + j) * 5 + 3];
        bool anyInv = (cntb != (float)HW);
        float rmin = anyInv ? pad : INFINITY;
        { float d = rmin - pad; tmpR[tid][81] = d * d; }
        for (int k = NB - 1; k >= 0; --k) {
            rmin = fminf(rmin, fB[tid * 82 + k + 1]);
            float d = rmin - SBb[k];
            tmpR[tid][k] = d * d;
        }
        float lmax = -INFINITY, sb = 0.f;
        for (int k = 0; k <= NB; ++k) {
            lmax = fmaxf(lmax, fA[tid * 82 + k]);
            float sk = (k < NB) ? SBb[k] : pad;
            float d = sk - lmax;
            sb += fminf(d * d, tmpR[tid][k]);
        }
        out8[tid] = sb;
    }

    // fold K1 stats partials (plain loads; K1->K2 dispatch boundary coherence)
    float v0 = 0.f, v1 = 0.f, v2 = 0.f, v3 = 0.f;
    if (tid < K1B) {
        const float* p5 = &ws[ST_OFF + tid * 5];
        v0 = p5[0]; v1 = p5[1]; v2 = p5[2]; v3 = p5[3];
    }
    float s0 = bsum1024(v0, red);
    float s1 = bsum1024(v1, red);
    float s2 = bsum1024(v2, red);
    float s3 = bsum1024(v3, red);
    // fold dirA block sums (atomic loads, fixed tree)
    float va_ = 0.f;
    if (tid < K2B) va_ = __hip_atomic_load(&ws[DA_OFF + tid], __ATOMIC_RELAXED, __HIP_MEMORY_SCOPE_AGENT);
    float sa = bsum1024(va_, red);

    if (tid == 0) {
        float sumB = 0.f;
        for (int i = 0; i < BB; ++i) sumB += out8[i];
        float m1 = s0 / s3, m2 = s1 / s3;
        float silog = 10.0f * sqrtf(fmaxf(m2 - 0.85f * m1 * m1, 0.0f));
        float l2 = sqrtf(s2 / s3);
        float chamfer = (sa + sumB) / (float)BB;
        out[0] = l2 + silog + chamfer;
    }
}

// ---------------------------------------------------------------------------
extern "C" void kernel_launch(void* const* d_in, const int* in_sizes, int n_in,
                              void* d_out, int out_size, void* d_ws, size_t ws_size,
                              hipStream_t stream) {
    (void)in_sizes; (void)n_in; (void)out_size; (void)ws_size;
    const float* pred = (const float*)d_in[0];
    const float* tgt  = (const float*)d_in[1];
    const float* bins = (const float*)d_in[2];
    const void*  mask = d_in[3];
    float* ws  = (float*)d_ws;
    float* out = (float*)d_out;

    k_stats<<<K1B, 256, 0, stream>>>(pred, tgt, mask, ws);
    k_chamfer<<<K2B, 1024, 0, stream>>>(tgt, bins, mask, ws, out);
}